// Round 8
// baseline (36.399 us; speedup 1.0000x reference)
//
#include <hip/hip_runtime.h>

// out[b,n,:] = relu([v_bn, emb[n]] @ W1 + b1) @ W2 + b2,  v_bn = abs_actions[b, asgn[b,n]]
// Split: base[n,h] = emb[n]@W1[1:,h] + b1[h]  (bf16 MFMA, r4-verified)
//        out[b,n]  = relu(base[n,:] + v*W1[0,:]) @ W2 + b2  (fp32 VALU)
// Round 8: phase 2 was LDS-read-bound (model: 64 quads x 4-5 b128/thread).
//   New phase 2: 64 threads x 8 b's x full-h (NO h-chunk, NO cross-thread combine
//   -- the r2/r3/r5 failures all had h-chunk+combine; full-h has passed 3x).
//   Weight reads amortized 8x, c read once: 32 reads/pair vs r4's 160.

constexpr int B_ = 32, A_ = 16, N_ = 10000, E_ = 256, H_ = 256;
constexpr int TN = 16, NBLK = N_ / TN;   // 625 blocks, 10000 exactly

typedef __attribute__((ext_vector_type(8))) short bf16x8;
typedef __attribute__((ext_vector_type(4))) float f32x4;

__device__ __align__(16) ushort g_w1t[H_ * E_];   // [h][k] bf16 of W1[1+k][h]

static __device__ __forceinline__ ushort f2bf(float x) {
    union { float f; unsigned u; } c; c.f = x;
    unsigned r = c.u + 0x7fff + ((c.u >> 16) & 1);   // RNE
    return (ushort)(r >> 16);
}

__global__ __launch_bounds__(256, 1) void prep_w1t_k(const float* __restrict__ W1) {
    __shared__ float tile[64][65];
    const int bk = blockIdx.x >> 2, bh = blockIdx.x & 3;
    const int tx = threadIdx.x & 63, ty = threadIdx.x >> 6;
    #pragma unroll
    for (int kk = ty; kk < 64; kk += 4)
        tile[kk][tx] = W1[(size_t)(1 + bk * 64 + kk) * H_ + bh * 64 + tx];
    __syncthreads();
    #pragma unroll
    for (int hh = ty; hh < 64; hh += 4)
        g_w1t[(size_t)(bh * 64 + hh) * E_ + bk * 64 + tx] = f2bf(tile[tx][hh]);
}

__global__ __launch_bounds__(256, 4) void decoder_main(
    const float* __restrict__ abs_actions,  // (32,16)
    const int*   __restrict__ asgn,         // (32,10000)
    const float* __restrict__ emb,          // (10000,256)
    const float* __restrict__ W1,           // (257,256)
    const float* __restrict__ b1,           // (256)
    const float* __restrict__ W2,           // (256,2)
    const float* __restrict__ b2,           // (2)
    float* __restrict__ out)                // (32,10000,2)
{
    __shared__ ushort eb[TN * 264];     // emb tile bf16, pitch 264
    __shared__ float  u[TN * 260];      // base tile f32, pitch 260
    __shared__ float  vals[B_ * 17];    // v[b][n], pitch 17
    __shared__ float  w1r[H_];          // W1 row 0
    __shared__ float  w2s[2 * H_];      // W2 flat [h*2+o]

    const int t  = threadIdx.x;
    const int n0 = blockIdx.x * TN;

    // ---- stage vals (r4-verified)
    #pragma unroll
    for (int q = 0; q < 2; ++q) {
        const int p = t + 256 * q, b = p >> 4, n = p & 15;
        vals[b * 17 + n] = abs_actions[b * A_ + asgn[(size_t)b * N_ + n0 + n]];
    }

    // ---- stage emb tile -> bf16 LDS (r4-verified)
    {
        const int row = t >> 4, col = (t & 15) << 4;
        const float4* src = reinterpret_cast<const float4*>(emb + (size_t)(n0 + row) * E_ + col);
        const float4 q0 = src[0], q1 = src[1], q2 = src[2], q3 = src[3];
        union { ushort us[16]; bf16x8 v[2]; } pk;
        const float f[16] = {q0.x,q0.y,q0.z,q0.w, q1.x,q1.y,q1.z,q1.w,
                             q2.x,q2.y,q2.z,q2.w, q3.x,q3.y,q3.z,q3.w};
        #pragma unroll
        for (int i = 0; i < 16; ++i) pk.us[i] = f2bf(f[i]);
        bf16x8* dst = reinterpret_cast<bf16x8*>(&eb[row * 264 + col]);
        dst[0] = pk.v[0]; dst[1] = pk.v[1];
    }
    w1r[t]       = W1[t];
    w2s[t]       = W2[t];
    w2s[256 + t] = W2[256 + t];
    __syncthreads();

    // ---- phase 1: base = emb @ W1[1:] + b1 (MFMA 16x16x32 bf16; r4-verified)
    {
        const int lane = t & 63, w = t >> 6;
        const int lr = lane & 15;
        const int lk = (lane >> 4) << 3;
        f32x4 acc[4];
        #pragma unroll
        for (int ct = 0; ct < 4; ++ct) {
            const float bv = b1[w * 64 + ct * 16 + lr];
            acc[ct] = (f32x4){bv, bv, bv, bv};
        }
        #pragma unroll
        for (int ks = 0; ks < 8; ++ks) {
            const bf16x8 af = *reinterpret_cast<const bf16x8*>(&eb[lr * 264 + ks * 32 + lk]);
            #pragma unroll
            for (int ct = 0; ct < 4; ++ct) {
                const bf16x8 bfv = *reinterpret_cast<const bf16x8*>(
                    &g_w1t[(size_t)(w * 64 + ct * 16 + lr) * E_ + ks * 32 + lk]);
                acc[ct] = __builtin_amdgcn_mfma_f32_16x16x32_bf16(af, bfv, acc[ct], 0, 0, 0);
            }
        }
        // D: col = lane&15, row = (lane>>4)*4 + r   [r4-verified]
        #pragma unroll
        for (int ct = 0; ct < 4; ++ct)
            #pragma unroll
            for (int r = 0; r < 4; ++r)
                u[((lane >> 4) * 4 + r) * 260 + w * 64 + ct * 16 + lr] = acc[ct][r];
    }
    __syncthreads();

    // ---- phase 2: 64 threads, each (n = t&15, bg = t>>4) x 8 b's, FULL h loop
    if (t < 64) {
        const int n  = t & 15;
        const int bg = t >> 4;                 // 0..3
        const float b20 = b2[0], b21 = b2[1];
        float vv[8], o0[8], o1[8];
        #pragma unroll
        for (int bi = 0; bi < 8; ++bi) {
            vv[bi] = vals[(bg * 8 + bi) * 17 + n];
            o0[bi] = 0.f; o1[bi] = 0.f;
        }

        const float* br = &u[n * 260];
        #pragma unroll 2
        for (int h = 0; h < 256; h += 4) {
            const float4 c  = *reinterpret_cast<const float4*>(&br[h]);
            const float4 wv = *reinterpret_cast<const float4*>(&w1r[h]);
            const float4 p0 = *reinterpret_cast<const float4*>(&w2s[2 * h]);
            const float4 p1 = *reinterpret_cast<const float4*>(&w2s[2 * h + 4]);
            #pragma unroll
            for (int bi = 0; bi < 8; ++bi) {
                const float v = vv[bi];
                const float r0 = fmaxf(fmaf(v, wv.x, c.x), 0.f);
                const float r1 = fmaxf(fmaf(v, wv.y, c.y), 0.f);
                const float r2 = fmaxf(fmaf(v, wv.z, c.z), 0.f);
                const float r3 = fmaxf(fmaf(v, wv.w, c.w), 0.f);
                o0[bi] = fmaf(r0, p0.x, o0[bi]);
                o1[bi] = fmaf(r0, p0.y, o1[bi]);
                o0[bi] = fmaf(r1, p0.z, o0[bi]);
                o1[bi] = fmaf(r1, p0.w, o1[bi]);
                o0[bi] = fmaf(r2, p1.x, o0[bi]);
                o1[bi] = fmaf(r2, p1.y, o1[bi]);
                o0[bi] = fmaf(r3, p1.z, o0[bi]);
                o1[bi] = fmaf(r3, p1.w, o1[bi]);
            }
        }

        #pragma unroll
        for (int bi = 0; bi < 8; ++bi) {
            const int b = bg * 8 + bi;
            float2 o; o.x = o0[bi] + b20; o.y = o1[bi] + b21;
            *reinterpret_cast<float2*>(out + ((size_t)b * N_ + n0 + n) * 2) = o;
        }
    }
}

extern "C" void kernel_launch(void* const* d_in, const int* in_sizes, int n_in,
                              void* d_out, int out_size, void* d_ws, size_t ws_size,
                              hipStream_t stream) {
    const float* abs_actions = (const float*)d_in[0];
    const int*   asgn        = (const int*)d_in[1];
    const float* emb         = (const float*)d_in[2];
    const float* W1          = (const float*)d_in[3];
    const float* b1          = (const float*)d_in[4];
    const float* W2          = (const float*)d_in[5];
    const float* b2          = (const float*)d_in[6];
    float*       out         = (float*)d_out;

    prep_w1t_k<<<16, 256, 0, stream>>>(W1);
    decoder_main<<<NBLK, 256, 0, stream>>>(abs_actions, asgn, emb, W1, b1, W2, b2, out);
}

// Round 9
// 30.001 us; speedup vs baseline: 1.2133x; 1.2133x over previous
//
#include <hip/hip_runtime.h>

// out[b,n,:] = relu([v_bn, emb[n]] @ W1 + b1) @ W2 + b2,  v_bn = abs_actions[b, asgn[b,n]]
// Split: base[n,h] = emb[n]@W1[1:,h] + b1[h]  (bf16 MFMA, r4-verified)
//        out[b,n]  = relu(base[n,:] + v*W1[0,:]) @ W2 + b2  (fp32 VALU)
// Round 9: phase 2 = (bg x n) threads, 2 b's each, FULL-h, no cross-thread combine.
//   All 256 threads busy (r8 left 3/4 waves idle); weight LDS reads are
//   same-address broadcasts; VALU-issue-bound ~4.4 us device-wide (was 15.7 LDS-bound).

constexpr int B_ = 32, A_ = 16, N_ = 10000, E_ = 256, H_ = 256;
constexpr int TN = 16, NBLK = N_ / TN;   // 625 blocks, 10000 exactly

typedef __attribute__((ext_vector_type(8))) short bf16x8;
typedef __attribute__((ext_vector_type(4))) float f32x4;

__device__ __align__(16) ushort g_w1t[H_ * E_];   // [h][k] bf16 of W1[1+k][h]

static __device__ __forceinline__ ushort f2bf(float x) {
    union { float f; unsigned u; } c; c.f = x;
    unsigned r = c.u + 0x7fff + ((c.u >> 16) & 1);   // RNE
    return (ushort)(r >> 16);
}

__global__ __launch_bounds__(256, 1) void prep_w1t_k(const float* __restrict__ W1) {
    __shared__ float tile[64][65];
    const int bk = blockIdx.x >> 2, bh = blockIdx.x & 3;
    const int tx = threadIdx.x & 63, ty = threadIdx.x >> 6;
    #pragma unroll
    for (int kk = ty; kk < 64; kk += 4)
        tile[kk][tx] = W1[(size_t)(1 + bk * 64 + kk) * H_ + bh * 64 + tx];
    __syncthreads();
    #pragma unroll
    for (int hh = ty; hh < 64; hh += 4)
        g_w1t[(size_t)(bh * 64 + hh) * E_ + bk * 64 + tx] = f2bf(tile[tx][hh]);
}

__global__ __launch_bounds__(256, 4) void decoder_main(
    const float* __restrict__ abs_actions,  // (32,16)
    const int*   __restrict__ asgn,         // (32,10000)
    const float* __restrict__ emb,          // (10000,256)
    const float* __restrict__ W1,           // (257,256)
    const float* __restrict__ b1,           // (256)
    const float* __restrict__ W2,           // (256,2)
    const float* __restrict__ b2,           // (2)
    float* __restrict__ out)                // (32,10000,2)
{
    __shared__ ushort eb[TN * 264];     // emb tile bf16, pitch 264
    __shared__ float  u[TN * 260];      // base tile f32, pitch 260
    __shared__ float  vals[B_ * 17];    // v[b][n], pitch 17
    __shared__ float  w1r[H_];          // W1 row 0
    __shared__ float  w2s[2 * H_];      // W2 flat [h*2+o]

    const int t  = threadIdx.x;
    const int n0 = blockIdx.x * TN;

    // ---- stage vals (r4-verified)
    #pragma unroll
    for (int q = 0; q < 2; ++q) {
        const int p = t + 256 * q, b = p >> 4, n = p & 15;
        vals[b * 17 + n] = abs_actions[b * A_ + asgn[(size_t)b * N_ + n0 + n]];
    }

    // ---- stage emb tile -> bf16 LDS (r4-verified)
    {
        const int row = t >> 4, col = (t & 15) << 4;
        const float4* src = reinterpret_cast<const float4*>(emb + (size_t)(n0 + row) * E_ + col);
        const float4 q0 = src[0], q1 = src[1], q2 = src[2], q3 = src[3];
        union { ushort us[16]; bf16x8 v[2]; } pk;
        const float f[16] = {q0.x,q0.y,q0.z,q0.w, q1.x,q1.y,q1.z,q1.w,
                             q2.x,q2.y,q2.z,q2.w, q3.x,q3.y,q3.z,q3.w};
        #pragma unroll
        for (int i = 0; i < 16; ++i) pk.us[i] = f2bf(f[i]);
        bf16x8* dst = reinterpret_cast<bf16x8*>(&eb[row * 264 + col]);
        dst[0] = pk.v[0]; dst[1] = pk.v[1];
    }
    w1r[t]       = W1[t];
    w2s[t]       = W2[t];
    w2s[256 + t] = W2[256 + t];
    __syncthreads();

    // ---- phase 1: base = emb @ W1[1:] + b1 (MFMA 16x16x32 bf16; r4-verified)
    {
        const int lane = t & 63, w = t >> 6;
        const int lr = lane & 15;
        const int lk = (lane >> 4) << 3;
        f32x4 acc[4];
        #pragma unroll
        for (int ct = 0; ct < 4; ++ct) {
            const float bv = b1[w * 64 + ct * 16 + lr];
            acc[ct] = (f32x4){bv, bv, bv, bv};
        }
        #pragma unroll
        for (int ks = 0; ks < 8; ++ks) {
            const bf16x8 af = *reinterpret_cast<const bf16x8*>(&eb[lr * 264 + ks * 32 + lk]);
            #pragma unroll
            for (int ct = 0; ct < 4; ++ct) {
                const bf16x8 bfv = *reinterpret_cast<const bf16x8*>(
                    &g_w1t[(size_t)(w * 64 + ct * 16 + lr) * E_ + ks * 32 + lk]);
                acc[ct] = __builtin_amdgcn_mfma_f32_16x16x32_bf16(af, bfv, acc[ct], 0, 0, 0);
            }
        }
        // D: col = lane&15, row = (lane>>4)*4 + r   [r4-verified]
        #pragma unroll
        for (int ct = 0; ct < 4; ++ct)
            #pragma unroll
            for (int r = 0; r < 4; ++r)
                u[((lane >> 4) * 4 + r) * 260 + w * 64 + ct * 16 + lr] = acc[ct][r];
    }
    __syncthreads();

    // ---- phase 2: thread = (bg = t>>4, n = t&15), 2 b's each, FULL-h loop
    {
        const int bg = t >> 4, n = t & 15;
        const float b20 = b2[0], b21 = b2[1];
        const float v0 = vals[(bg * 2 + 0) * 17 + n];
        const float v1 = vals[(bg * 2 + 1) * 17 + n];
        float o00 = 0.f, o01 = 0.f, o10 = 0.f, o11 = 0.f;

        const float* br = &u[n * 260];
        #pragma unroll 4
        for (int h = 0; h < 256; h += 4) {
            const float4 c  = *reinterpret_cast<const float4*>(&br[h]);
            const float4 wv = *reinterpret_cast<const float4*>(&w1r[h]);
            const float4 p0 = *reinterpret_cast<const float4*>(&w2s[2 * h]);
            const float4 p1 = *reinterpret_cast<const float4*>(&w2s[2 * h + 4]);
            // b = bg*2
            {
                const float r0 = fmaxf(fmaf(v0, wv.x, c.x), 0.f);
                const float r1 = fmaxf(fmaf(v0, wv.y, c.y), 0.f);
                const float r2 = fmaxf(fmaf(v0, wv.z, c.z), 0.f);
                const float r3 = fmaxf(fmaf(v0, wv.w, c.w), 0.f);
                o00 = fmaf(r0, p0.x, o00);
                o01 = fmaf(r0, p0.y, o01);
                o00 = fmaf(r1, p0.z, o00);
                o01 = fmaf(r1, p0.w, o01);
                o00 = fmaf(r2, p1.x, o00);
                o01 = fmaf(r2, p1.y, o01);
                o00 = fmaf(r3, p1.z, o00);
                o01 = fmaf(r3, p1.w, o01);
            }
            // b = bg*2 + 1
            {
                const float r0 = fmaxf(fmaf(v1, wv.x, c.x), 0.f);
                const float r1 = fmaxf(fmaf(v1, wv.y, c.y), 0.f);
                const float r2 = fmaxf(fmaf(v1, wv.z, c.z), 0.f);
                const float r3 = fmaxf(fmaf(v1, wv.w, c.w), 0.f);
                o10 = fmaf(r0, p0.x, o10);
                o11 = fmaf(r0, p0.y, o11);
                o10 = fmaf(r1, p0.z, o10);
                o11 = fmaf(r1, p0.w, o11);
                o10 = fmaf(r2, p1.x, o10);
                o11 = fmaf(r2, p1.y, o11);
                o10 = fmaf(r3, p1.z, o10);
                o11 = fmaf(r3, p1.w, o11);
            }
        }

        float2 oa; oa.x = o00 + b20; oa.y = o01 + b21;
        float2 ob; ob.x = o10 + b20; ob.y = o11 + b21;
        *reinterpret_cast<float2*>(out + ((size_t)(bg * 2 + 0) * N_ + n0 + n) * 2) = oa;
        *reinterpret_cast<float2*>(out + ((size_t)(bg * 2 + 1) * N_ + n0 + n) * 2) = ob;
    }
}

extern "C" void kernel_launch(void* const* d_in, const int* in_sizes, int n_in,
                              void* d_out, int out_size, void* d_ws, size_t ws_size,
                              hipStream_t stream) {
    const float* abs_actions = (const float*)d_in[0];
    const int*   asgn        = (const int*)d_in[1];
    const float* emb         = (const float*)d_in[2];
    const float* W1          = (const float*)d_in[3];
    const float* b1          = (const float*)d_in[4];
    const float* W2          = (const float*)d_in[5];
    const float* b2          = (const float*)d_in[6];
    float*       out         = (float*)d_out;

    prep_w1t_k<<<16, 256, 0, stream>>>(W1);
    decoder_main<<<NBLK, 256, 0, stream>>>(abs_actions, asgn, emb, W1, b1, W2, b2, out);
}